// Round 1
// baseline (153.028 us; speedup 1.0000x reference)
//
#include <hip/hip_runtime.h>
#include <math.h>

// dist[b,n] = sum_d softplus(fw[d]) * |q[b,d] - X[n,d]|
// Trick: softplus(fw) > 0, so w*|q-x| == |w*q - w*x|; pre-scale q (LDS) and x (regs).
// Inner body = v_sub_f32 + v_add_f32 with abs modifier -> 2 VALU / element.

constexpr int D = 64;
constexpr int BCHUNK = 16;    // b-values per block (blockIdx.y)
constexpr int NTHREADS = 256; // X rows per block (one row per thread)

__global__ __launch_bounds__(NTHREADS, 4)
void fdist_kernel(const float* __restrict__ q,
                  const float* __restrict__ X,
                  const float* __restrict__ fw,
                  float* __restrict__ out, int N) {
    __shared__ float ws[D];
    __shared__ float qs[BCHUNK][D];

    const int t = threadIdx.x;
    const int bbase = blockIdx.y * BCHUNK;
    const int n = blockIdx.x * NTHREADS + t;

    // Phase 1: softplus of feature weights (stable form)
    if (t < D) {
        float x = fw[t];
        ws[t] = fmaxf(x, 0.f) + log1pf(expf(-fabsf(x)));
    }
    __syncthreads();

    // Phase 2: pre-scaled q tile for this block's b-chunk
    for (int i = t; i < BCHUNK * D; i += NTHREADS) {
        const int bi = i >> 6;      // i / 64
        const int d  = i & (D - 1); // i % 64
        qs[bi][d] = ws[d] * q[(size_t)(bbase + bi) * D + d];
    }
    __syncthreads();

    if (n >= N) return;

    // Load this thread's X row and scale by ws
    float4 xs[D / 4];
    const float4* xrow = reinterpret_cast<const float4*>(X + (size_t)n * D);
#pragma unroll
    for (int i = 0; i < D / 4; ++i) xs[i] = xrow[i];
#pragma unroll
    for (int i = 0; i < D / 4; ++i) {
        xs[i].x *= ws[4 * i + 0];
        xs[i].y *= ws[4 * i + 1];
        xs[i].z *= ws[4 * i + 2];
        xs[i].w *= ws[4 * i + 3];
    }

    // Main loop: 16 b-values x 64 d. q reads are wave-uniform LDS broadcasts.
#pragma unroll
    for (int bi = 0; bi < BCHUNK; ++bi) {
        float acc = 0.f;
#pragma unroll
        for (int i = 0; i < D / 4; ++i) {
            const float4 qv = *reinterpret_cast<const float4*>(&qs[bi][4 * i]);
            acc += fabsf(qv.x - xs[i].x);
            acc += fabsf(qv.y - xs[i].y);
            acc += fabsf(qv.z - xs[i].z);
            acc += fabsf(qv.w - xs[i].w);
        }
        out[(size_t)(bbase + bi) * N + n] = acc;
    }
}

extern "C" void kernel_launch(void* const* d_in, const int* in_sizes, int n_in,
                              void* d_out, int out_size, void* d_ws, size_t ws_size,
                              hipStream_t stream) {
    const float* q  = (const float*)d_in[0];
    const float* X  = (const float*)d_in[1];
    const float* fw = (const float*)d_in[2];
    float* out = (float*)d_out;

    const int B = in_sizes[0] / D;  // 64
    const int N = in_sizes[1] / D;  // 50000

    dim3 grid((N + NTHREADS - 1) / NTHREADS, B / BCHUNK);
    fdist_kernel<<<grid, dim3(NTHREADS), 0, stream>>>(q, X, fw, out, N);
}

// Round 2
// 22.007 us; speedup vs baseline: 6.9536x; 6.9536x over previous
//
#include <hip/hip_runtime.h>
#include <math.h>

// dist[b,n] = sum_d softplus(fw[d]) * |q[b,d] - X[n,d]|
//           = sum_d |ws[d]*q[b,d] - ws[d]*X[n,d]|   (softplus > 0)
// Round 2: coalesce X loads via double-buffered LDS staging (64-row chunks),
// XCD-swizzled 1-D grid with x-outer/y-inner decode for L2 reuse of X across
// the 4 b-chunks, 4-way accumulator chains.

constexpr int D = 64;
constexpr int BCHUNK = 16;   // b-values per block
constexpr int NT = 256;      // threads/block, 1 X row per thread
constexpr int ROWS = 256;    // X rows per block
constexpr int CH = 64;       // rows per staging chunk
constexpr int PAD = 68;      // padded LDS row stride (floats)

__global__ __launch_bounds__(NT, 3)
void fdist_kernel(const float* __restrict__ q,
                  const float* __restrict__ X,
                  const float* __restrict__ fw,
                  float* __restrict__ out, int N) {
    __shared__ float ws[D];
    __shared__ float qs[BCHUNK][D];
    __shared__ float xtile[CH][PAD];

    const int t = threadIdx.x;
    const int wave = t >> 6;
    const int lane = t & 63;

    // ---- bijective XCD-chunked swizzle (m204 form), then x-outer/y-inner ----
    const int nwg = gridDim.x;
    const int orig = blockIdx.x;
    const int q8 = nwg >> 3, r8 = nwg & 7;
    const int xcd = orig & 7, pos = orig >> 3;
    const int wg = (xcd < r8 ? xcd * (q8 + 1) : r8 * (q8 + 1) + (xcd - r8) * q8) + pos;
    const int xb = wg >> 2;          // n-block: consecutive wg on one XCD share x-range
    const int yb = wg & 3;           // b-chunk
    const int bbase = yb * BCHUNK;
    const int nbase = xb * ROWS;
    const int n = nbase + t;

    // ---- issue first two X chunks early (coalesced: 64 lanes -> 1 KB contig) ----
    // chunk c, sub-load jj: this thread loads row (c*4+jj)*16 + t/16, cols (t%15)*4..
    const int rsub = t >> 4;         // 0..15
    const int col  = t & 15;         // float4 column within row
    const float4* Xv = reinterpret_cast<const float4*>(X);

    float4 buf[2][4];
#pragma unroll
    for (int jj = 0; jj < 4; ++jj) {
        int grow = nbase + jj * 16 + rsub;
        grow = grow < N ? grow : N - 1;
        buf[0][jj] = Xv[(size_t)grow * 16 + col];
    }
#pragma unroll
    for (int jj = 0; jj < 4; ++jj) {
        int grow = nbase + CH + jj * 16 + rsub;
        grow = grow < N ? grow : N - 1;
        buf[1][jj] = Xv[(size_t)grow * 16 + col];
    }

    // ---- softplus(fw) ----
    if (t < D) {
        float x = fw[t];
        ws[t] = fmaxf(x, 0.f) + log1pf(expf(-fabsf(x)));
    }
    __syncthreads();

    // ---- pre-scaled q tile (coalesced: q[bbase*64 + i] contiguous) ----
#pragma unroll
    for (int i = t; i < BCHUNK * D; i += NT) {
        qs[i >> 6][i & (D - 1)] = ws[i & (D - 1)] * q[(size_t)bbase * D + i];
    }

    // this thread's per-column weights (col fixed for all its staging stores)
    const float4 wv = *reinterpret_cast<const float4*>(&ws[col * 4]);

    // ---- staged chunks: write scaled tile, wave c copies its rows to regs ----
    float4 xs[16];
#pragma unroll
    for (int c = 0; c < 4; ++c) {
#pragma unroll
        for (int jj = 0; jj < 4; ++jj) {
            float4 v = buf[c & 1][jj];
            v.x *= wv.x; v.y *= wv.y; v.z *= wv.z; v.w *= wv.w;
            *reinterpret_cast<float4*>(&xtile[jj * 16 + rsub][col * 4]) = v;
        }
        if (c + 2 < 4) {  // prefetch chunk c+2 into the buffer just drained
#pragma unroll
            for (int jj = 0; jj < 4; ++jj) {
                int grow = nbase + (c + 2) * CH + jj * 16 + rsub;
                grow = grow < N ? grow : N - 1;
                buf[c & 1][jj] = Xv[(size_t)grow * 16 + col];
            }
        }
        __syncthreads();
        if (wave == c) {
#pragma unroll
            for (int i = 0; i < 16; ++i)
                xs[i] = *reinterpret_cast<const float4*>(&xtile[lane][i * 4]);
        }
        __syncthreads();
    }

    // ---- main loop: 16 b-values, q via broadcast LDS reads, 4 acc chains ----
#pragma unroll
    for (int bi = 0; bi < BCHUNK; ++bi) {
        float ax = 0.f, ay = 0.f, az = 0.f, aw = 0.f;
#pragma unroll
        for (int i = 0; i < 16; ++i) {
            const float4 qv = *reinterpret_cast<const float4*>(&qs[bi][4 * i]);
            ax += fabsf(qv.x - xs[i].x);
            ay += fabsf(qv.y - xs[i].y);
            az += fabsf(qv.z - xs[i].z);
            aw += fabsf(qv.w - xs[i].w);
        }
        if (n < N) out[(size_t)(bbase + bi) * N + n] = (ax + ay) + (az + aw);
    }
}

extern "C" void kernel_launch(void* const* d_in, const int* in_sizes, int n_in,
                              void* d_out, int out_size, void* d_ws, size_t ws_size,
                              hipStream_t stream) {
    const float* q  = (const float*)d_in[0];
    const float* X  = (const float*)d_in[1];
    const float* fw = (const float*)d_in[2];
    float* out = (float*)d_out;

    const int B = in_sizes[0] / D;  // 64
    const int N = in_sizes[1] / D;  // 50000

    const int nxblk = (N + ROWS - 1) / ROWS;      // 196
    const int nwg = nxblk * (B / BCHUNK);         // 784
    fdist_kernel<<<dim3(nwg), dim3(NT), 0, stream>>>(q, X, fw, out, N);
}